// Round 1
// baseline (5756.989 us; speedup 1.0000x reference)
//
#include <hip/hip_runtime.h>

// Problem constants
#define BDIM 256   // batch
#define TDIM 256   // timesteps
#define IDIM 512   // input dim
#define HDIM 512   // hidden dim
#define G4   2048  // 4*H gate rows

typedef __attribute__((ext_vector_type(4))) float f32x4;
typedef __attribute__((ext_vector_type(8))) short short8;     // 8 bf16 (4 VGPRs) MFMA frag
typedef __attribute__((ext_vector_type(8))) unsigned short u16x8;
typedef __attribute__((ext_vector_type(4))) unsigned short u16x4;

__device__ __forceinline__ unsigned short f2bf(float f) {
  union { float f; unsigned u; } v; v.f = f;
  unsigned r = v.u + 0x7FFFu + ((v.u >> 16) & 1u);   // RNE
  return (unsigned short)(r >> 16);
}
__device__ __forceinline__ float bf2f(unsigned short h) {
  union { unsigned u; float f; } v; v.u = ((unsigned)h) << 16; return v.f;
}
__device__ __forceinline__ float sigmoidf_fast(float x) {
  return 1.0f / (1.0f + __expf(-x));
}
__device__ __forceinline__ float tanhf_fast(float x) {
  float e = __expf(2.0f * x);          // +/-inf handled: 1 - 2/inf = 1
  return 1.0f - 2.0f / (e + 1.0f);
}

// ---------------------------------------------------------------------------
// Phase 1: xg[t*B + b][g] = sum_i x[b,t,i]*W_ih[g,i] + b_ih[g] + b_hh[g]  (bf16 out)
// 128x128 tile, BK=32, 16x16x32 bf16 MFMA, fp32->bf16 conversion in staging.
// Output row remap m=(b*T+t) -> t*B+b so the scan reads contiguous per-t slabs.
// ---------------------------------------------------------------------------
__global__ void __launch_bounds__(256, 2) xg_gemm(
    const float* __restrict__ X, const float* __restrict__ Wih,
    const float* __restrict__ b_ih, const float* __restrict__ b_hh,
    unsigned short* __restrict__ xg)
{
  __shared__ unsigned short sA[128][40];   // +8 pad: 2-way banks only
  __shared__ unsigned short sB[128][40];

  const int tid  = threadIdx.x;
  const int lane = tid & 63;
  const int wave = tid >> 6;
  const int l15  = lane & 15;
  const int quad = lane >> 4;
  const int nt = blockIdx.x;           // 16 n-tiles
  const int mt = blockIdx.y;           // 512 m-tiles
  const int wm = (wave >> 1) * 64;     // wave 2x2 grid, 64x64 each
  const int wn = (wave & 1) * 64;

  const int r    = tid >> 1;           // staging row 0..127
  const int half = (tid & 1) * 16;     // staging col offset {0,16}

  const float* arow = X   + (size_t)(mt * 128 + r) * 512 + half;
  const float* brow = Wih + (size_t)(nt * 128 + r) * 512 + half;

  f32x4 acc[4][4];
  #pragma unroll
  for (int i = 0; i < 4; ++i)
    #pragma unroll
    for (int j = 0; j < 4; ++j)
      acc[i][j] = (f32x4){0.f, 0.f, 0.f, 0.f};

  for (int kt = 0; kt < 16; ++kt) {
    const float* ap = arow + kt * 32;
    const float* bp = brow + kt * 32;
    #pragma unroll
    for (int i = 0; i < 4; ++i) {
      float4 a = ((const float4*)ap)[i];
      u16x4 av = { f2bf(a.x), f2bf(a.y), f2bf(a.z), f2bf(a.w) };
      *(u16x4*)&sA[r][half + i * 4] = av;
      float4 b = ((const float4*)bp)[i];
      u16x4 bv = { f2bf(b.x), f2bf(b.y), f2bf(b.z), f2bf(b.w) };
      *(u16x4*)&sB[r][half + i * 4] = bv;
    }
    __syncthreads();

    short8 af[4], bfr[4];
    #pragma unroll
    for (int i = 0; i < 4; ++i) {
      af[i]  = *(const short8*)&sA[wm + i * 16 + l15][quad * 8];
      bfr[i] = *(const short8*)&sB[wn + i * 16 + l15][quad * 8];
    }
    #pragma unroll
    for (int am = 0; am < 4; ++am)
      #pragma unroll
      for (int an = 0; an < 4; ++an)
        acc[am][an] = __builtin_amdgcn_mfma_f32_16x16x32_bf16(
            af[am], bfr[an], acc[am][an], 0, 0, 0);
    __syncthreads();
  }

  // Epilogue: bias add, bf16 store with (b,t)->(t,b) row remap.
  float biasv[4];
  #pragma unroll
  for (int an = 0; an < 4; ++an) {
    int n = nt * 128 + wn + an * 16 + l15;
    biasv[an] = b_ih[n] + b_hh[n];
  }
  #pragma unroll
  for (int am = 0; am < 4; ++am) {
    #pragma unroll
    for (int reg = 0; reg < 4; ++reg) {
      int m = mt * 128 + wm + am * 16 + quad * 4 + reg;   // m = b*T + t
      size_t base = (size_t)((m & 255) * 256 + (m >> 8)) * G4;  // row = t*B + b
      #pragma unroll
      for (int an = 0; an < 4; ++an) {
        int n = nt * 128 + wn + an * 16 + l15;
        xg[base + n] = f2bf(acc[am][an][reg] + biasv[an]);
      }
    }
  }
}

// ---------------------------------------------------------------------------
// Phase 2: persistent scan. 256 WGs x 256 thr; WG (bb,jb): batch rows bb*32..+32,
// h-cols jb*16..+16 (gate rows q*512+jb*16+j, q=i,f,g,o handled by wave q).
// W_hh B-frags live in registers for all 256 steps; c in thread registers;
// h ping-pongs through global bf16 buffers; per-batch-block 32-WG barriers.
// ---------------------------------------------------------------------------
__global__ void __launch_bounds__(256, 1) lstm_scan(
    const float* __restrict__ Whh, const unsigned short* __restrict__ xg,
    unsigned short* __restrict__ hbuf0, unsigned short* __restrict__ hbuf1,
    unsigned int* __restrict__ counters)
{
  __shared__ unsigned short sH[32][520];   // h slice, +8 pad
  __shared__ float sG[32][64];             // MFMA out -> gate-math exchange

  const int tid  = threadIdx.x;
  const int lane = tid & 63;
  const int wave = tid >> 6;        // = gate type q
  const int l15  = lane & 15;
  const int quad = lane >> 4;
  const int bb = blockIdx.x >> 5;   // batch block 0..7
  const int jb = blockIdx.x & 31;   // j block 0..31
  const int bbase = bb * 32;

  // One-time: W_hh gate rows (q=wave, j=l15) -> 16 register B-frags per lane.
  short8 bfrag[16];
  {
    const float* wrow = Whh + (size_t)(wave * 512 + jb * 16 + l15) * 512;
    #pragma unroll
    for (int ks = 0; ks < 16; ++ks) {
      const float* p = wrow + ks * 32 + quad * 8;
      float4 f0 = ((const float4*)p)[0];
      float4 f1 = ((const float4*)p)[1];
      short8 v;
      v[0] = (short)f2bf(f0.x); v[1] = (short)f2bf(f0.y);
      v[2] = (short)f2bf(f0.z); v[3] = (short)f2bf(f0.w);
      v[4] = (short)f2bf(f1.x); v[5] = (short)f2bf(f1.y);
      v[6] = (short)f2bf(f1.z); v[7] = (short)f2bf(f1.w);
      bfrag[ks] = v;
    }
  }

  float c0 = 0.f, c1 = 0.f;        // cell state: (b=tid>>4, j=tid&15) and b+16
  const int gj = tid & 15;
  const int gb = tid >> 4;
  unsigned int* cnt = counters + bb * 32;   // 128B-spaced counters

  for (int t = 0; t < TDIM; ++t) {
    const unsigned short* hsrc = (t & 1) ? hbuf1 : hbuf0;
    unsigned short* hdst = (t & 1) ? hbuf0 : hbuf1;

    // Stage h slice [32][512] bf16 (32 KB, coalesced 16B chunks).
    const unsigned short* src = hsrc + (size_t)bbase * 512;
    #pragma unroll
    for (int i = 0; i < 8; ++i) {
      int c = i * 256 + tid;
      u16x8 v = *(const u16x8*)(src + c * 8);
      *(u16x8*)&sH[c >> 6][(c & 63) * 8] = v;
    }
    __syncthreads();

    // G = Hslice @ Whh_slice^T : wave q does N-tile q, both M-tiles.
    f32x4 acc0 = {0.f,0.f,0.f,0.f}, acc1 = {0.f,0.f,0.f,0.f};
    #pragma unroll
    for (int ks = 0; ks < 16; ++ks) {
      int koff = ks * 32 + quad * 8;
      short8 a0 = *(const short8*)&sH[l15][koff];
      short8 a1 = *(const short8*)&sH[16 + l15][koff];
      acc0 = __builtin_amdgcn_mfma_f32_16x16x32_bf16(a0, bfrag[ks], acc0, 0, 0, 0);
      acc1 = __builtin_amdgcn_mfma_f32_16x16x32_bf16(a1, bfrag[ks], acc1, 0, 0, 0);
    }
    {
      int col = wave * 16 + l15;   // C/D: row=quad*4+reg, col=l15 (m89-verified)
      #pragma unroll
      for (int rr = 0; rr < 4; ++rr) {
        sG[quad * 4 + rr][col]      = acc0[rr];
        sG[16 + quad * 4 + rr][col] = acc1[rr];
      }
    }
    __syncthreads();

    // Gate math: each thread owns 2 (b,j) cells; i,f,g,o at sG cols q*16+j.
    const unsigned short* xgt = xg + (size_t)t * BDIM * G4;
    #pragma unroll
    for (int e = 0; e < 2; ++e) {
      int b  = gb + e * 16;
      int bg = bbase + b;
      const unsigned short* xrow = xgt + (size_t)bg * G4 + jb * 16 + gj;
      float gi = sG[b][gj]      + bf2f(xrow[0]);
      float gf = sG[b][16 + gj] + bf2f(xrow[512]);
      float gg = sG[b][32 + gj] + bf2f(xrow[1024]);
      float go = sG[b][48 + gj] + bf2f(xrow[1536]);
      float iv = sigmoidf_fast(gi);
      float fv = sigmoidf_fast(gf);
      float gv = tanhf_fast(gg);
      float ov = sigmoidf_fast(go);
      float cc = fv * (e ? c1 : c0) + iv * gv;
      if (e) c1 = cc; else c0 = cc;
      float hh = ov * tanhf_fast(cc);
      hdst[(size_t)bg * 512 + jb * 16 + gj] = f2bf(hh);
    }

    // Sub-grid barrier over the 32 WGs sharing this batch block.
    // __syncthreads drains all stores to L2 (vmcnt(0) before s_barrier);
    // tid0's __threadfence (agent acq_rel) writes back the XCD L2 -> L3.
    __syncthreads();
    if (tid == 0) {
      __threadfence();
      __hip_atomic_fetch_add(cnt, 1u, __ATOMIC_RELEASE, __HIP_MEMORY_SCOPE_AGENT);
      const unsigned target = 32u * (unsigned)(t + 1);
      while (__hip_atomic_load(cnt, __ATOMIC_ACQUIRE, __HIP_MEMORY_SCOPE_AGENT) < target) {
        __builtin_amdgcn_s_sleep(1);
      }
    }
    __syncthreads();
  }
}

// ---------------------------------------------------------------------------
// Head: out[b] = h_last[b,:] . fc_w + fc_b
// ---------------------------------------------------------------------------
__global__ void head_kernel(const unsigned short* __restrict__ h,
                            const float* __restrict__ fc_w,
                            const float* __restrict__ fc_b,
                            float* __restrict__ out)
{
  const int b = blockIdx.x;
  const int lane = threadIdx.x;
  const unsigned short* hr = h + (size_t)b * 512;
  float s = 0.f;
  #pragma unroll
  for (int i = 0; i < 8; ++i) {
    int idx = lane + i * 64;
    s += bf2f(hr[idx]) * fc_w[idx];
  }
  #pragma unroll
  for (int off = 32; off > 0; off >>= 1) s += __shfl_down(s, off);
  if (lane == 0) out[b] = s + fc_b[0];
}

// ---------------------------------------------------------------------------
extern "C" void kernel_launch(void* const* d_in, const int* in_sizes, int n_in,
                              void* d_out, int out_size, void* d_ws, size_t ws_size,
                              hipStream_t stream) {
  const float* x    = (const float*)d_in[0];
  const float* W_ih = (const float*)d_in[1];
  const float* W_hh = (const float*)d_in[2];
  const float* b_ih = (const float*)d_in[3];
  const float* b_hh = (const float*)d_in[4];
  const float* fc_w = (const float*)d_in[5];
  const float* fc_b = (const float*)d_in[6];
  float* out = (float*)d_out;

  // Workspace layout (needs ~269 MB):
  //   [0, 268435456)              xg bf16, layout [t][b][g]
  //   [+0, +262144)               hbuf0 bf16 [256][512]
  //   [+262144, +524288)          hbuf1
  //   [+524288, +525312)          8 barrier counters, 128B apart
  const size_t XG_BYTES = (size_t)BDIM * TDIM * G4 * 2;  // 268435456
  const size_t HB_BYTES = (size_t)BDIM * HDIM * 2;       // 262144
  char* ws = (char*)d_ws;
  unsigned short* xg     = (unsigned short*)ws;
  unsigned short* hbuf0  = (unsigned short*)(ws + XG_BYTES);
  unsigned short* hbuf1  = (unsigned short*)(ws + XG_BYTES + HB_BYTES);
  unsigned int*   counters = (unsigned int*)(ws + XG_BYTES + 2 * HB_BYTES);

  // Zero h0 + counters (ws is poisoned 0xAA before every launch).
  hipMemsetAsync(ws + XG_BYTES, 0, 2 * HB_BYTES + 1024, stream);

  xg_gemm<<<dim3(16, 512), 256, 0, stream>>>(x, W_ih, b_ih, b_hh, xg);
  // grid=256 blocks, 1/CU (LDS 41.5KB, launch_bounds(256,1)) -> co-resident.
  lstm_scan<<<dim3(256), 256, 0, stream>>>(W_hh, xg, hbuf0, hbuf1, counters);
  // T=256 even: final h is in hbuf0.
  head_kernel<<<dim3(BDIM), 64, 0, stream>>>(hbuf0, fc_w, fc_b, out);
}

// Round 2
// 2279.991 us; speedup vs baseline: 2.5250x; 2.5250x over previous
//
#include <hip/hip_runtime.h>

// Problem constants
#define BDIM 256   // batch
#define TDIM 256   // timesteps
#define IDIM 512   // input dim
#define HDIM 512   // hidden dim
#define G4   2048  // 4*H gate rows

typedef __attribute__((ext_vector_type(4))) float f32x4;
typedef __attribute__((ext_vector_type(8))) short short8;     // 8 bf16 (4 VGPRs) MFMA frag
typedef __attribute__((ext_vector_type(8))) unsigned short u16x8;
typedef __attribute__((ext_vector_type(4))) unsigned short u16x4;

__device__ __forceinline__ unsigned short f2bf(float f) {
  union { float f; unsigned u; } v; v.f = f;
  unsigned r = v.u + 0x7FFFu + ((v.u >> 16) & 1u);   // RNE
  return (unsigned short)(r >> 16);
}
__device__ __forceinline__ float bf2f(unsigned short h) {
  union { unsigned u; float f; } v; v.u = ((unsigned)h) << 16; return v.f;
}
__device__ __forceinline__ float sigmoidf_fast(float x) {
  return 1.0f / (1.0f + __expf(-x));
}
__device__ __forceinline__ float tanhf_fast(float x) {
  float e = __expf(2.0f * x);          // +/-inf handled: 1 - 2/inf = 1
  return 1.0f - 2.0f / (e + 1.0f);
}

// ---------------------------------------------------------------------------
// Phase 1: xg = x @ W_ih^T + b_ih + b_hh  (bf16 out), scan-blocked layout:
//   xg[((t*8+bb)*32+jb)*2048 + q*512 + br*16 + j]   (bb=b>>5, br=b&31)
// so scan WG (bb,jb) reads one contiguous 4KB block per step, coalesced.
// ---------------------------------------------------------------------------
__global__ void __launch_bounds__(256, 2) xg_gemm(
    const float* __restrict__ X, const float* __restrict__ Wih,
    const float* __restrict__ b_ih, const float* __restrict__ b_hh,
    unsigned short* __restrict__ xg)
{
  __shared__ unsigned short sA[128][40];   // +8 pad: 2-way banks only
  __shared__ unsigned short sB[128][40];

  const int tid  = threadIdx.x;
  const int lane = tid & 63;
  const int wave = tid >> 6;
  const int l15  = lane & 15;
  const int quad = lane >> 4;
  const int nt = blockIdx.x;           // 16 n-tiles
  const int mt = blockIdx.y;           // 512 m-tiles
  const int wm = (wave >> 1) * 64;     // wave 2x2 grid, 64x64 each
  const int wn = (wave & 1) * 64;

  const int r    = tid >> 1;           // staging row 0..127
  const int half = (tid & 1) * 16;     // staging col offset {0,16}

  const float* arow = X   + (size_t)(mt * 128 + r) * 512 + half;
  const float* brow = Wih + (size_t)(nt * 128 + r) * 512 + half;

  f32x4 acc[4][4];
  #pragma unroll
  for (int i = 0; i < 4; ++i)
    #pragma unroll
    for (int j = 0; j < 4; ++j)
      acc[i][j] = (f32x4){0.f, 0.f, 0.f, 0.f};

  for (int kt = 0; kt < 16; ++kt) {
    const float* ap = arow + kt * 32;
    const float* bp = brow + kt * 32;
    #pragma unroll
    for (int i = 0; i < 4; ++i) {
      float4 a = ((const float4*)ap)[i];
      u16x4 av = { f2bf(a.x), f2bf(a.y), f2bf(a.z), f2bf(a.w) };
      *(u16x4*)&sA[r][half + i * 4] = av;
      float4 b = ((const float4*)bp)[i];
      u16x4 bv = { f2bf(b.x), f2bf(b.y), f2bf(b.z), f2bf(b.w) };
      *(u16x4*)&sB[r][half + i * 4] = bv;
    }
    __syncthreads();

    short8 af[4], bfr[4];
    #pragma unroll
    for (int i = 0; i < 4; ++i) {
      af[i]  = *(const short8*)&sA[wm + i * 16 + l15][quad * 8];
      bfr[i] = *(const short8*)&sB[wn + i * 16 + l15][quad * 8];
    }
    #pragma unroll
    for (int am = 0; am < 4; ++am)
      #pragma unroll
      for (int an = 0; an < 4; ++an)
        acc[am][an] = __builtin_amdgcn_mfma_f32_16x16x32_bf16(
            af[am], bfr[an], acc[am][an], 0, 0, 0);
    __syncthreads();
  }

  // Epilogue: bias add, bf16 store into scan-blocked layout.
  float biasv[4];
  #pragma unroll
  for (int an = 0; an < 4; ++an) {
    int n = nt * 128 + wn + an * 16 + l15;
    biasv[an] = b_ih[n] + b_hh[n];
  }
  #pragma unroll
  for (int am = 0; am < 4; ++am) {
    #pragma unroll
    for (int reg = 0; reg < 4; ++reg) {
      int m = mt * 128 + wm + am * 16 + quad * 4 + reg;   // m = b*T + t
      int b = m >> 8, t = m & 255;
      size_t blk = (size_t)(t * 8 + (b >> 5)) * 32;
      #pragma unroll
      for (int an = 0; an < 4; ++an) {
        int n = nt * 128 + wn + an * 16 + l15;
        int q = n >> 9, jb = (n >> 4) & 31, j = n & 15;
        size_t off = (blk + jb) * 2048 + (size_t)q * 512 + (b & 31) * 16 + j;
        xg[off] = f2bf(acc[am][an][reg] + biasv[an]);
      }
    }
  }
}

// ---------------------------------------------------------------------------
// Phase 2: persistent scan. 256 WGs x 256 thr; WG (bb,jb): batch rows bb*32..+32,
// h-cols jb*16..+16 (gate rows q*512+jb*16+j, handled by wave q).
// W_hh B-frags in registers for all 256 steps; c in thread registers.
// h communicated via RELAXED agent-scope atomics (sc1: bypass L1/L2, coherent
// at MALL across XCDs). NO acquire/release fences anywhere -> no buffer_inv /
// buffer_wbl2 (those destroyed L2 in R1: 20us/step, 775MB HBM fetch).
// Barrier: per-batch-block 32-WG monotonic counter, relaxed fetch_add + poll;
// __syncthreads' vmcnt(0) drain before the add orders the sc1 h-stores.
// ---------------------------------------------------------------------------
__global__ void __launch_bounds__(256, 1) lstm_scan(
    const float* __restrict__ Whh, const unsigned short* __restrict__ xg,
    unsigned short* __restrict__ hbuf0, unsigned short* __restrict__ hbuf1,
    unsigned int* __restrict__ counters)
{
  __shared__ unsigned short sH[32][520];   // h slice, +8 pad
  __shared__ float sG[32][64];             // MFMA out -> gate-math exchange

  const int tid  = threadIdx.x;
  const int lane = tid & 63;
  const int wave = tid >> 6;        // = gate type q for MFMA
  const int l15  = lane & 15;
  const int quad = lane >> 4;
  const int bb = blockIdx.x >> 5;   // batch block 0..7
  const int jb = blockIdx.x & 31;   // j block 0..31
  const int bbase = bb * 32;

  // One-time: W_hh gate rows (q=wave, j=l15) -> 16 register B-frags per lane.
  short8 bfrag[16];
  {
    const float* wrow = Whh + (size_t)(wave * 512 + jb * 16 + l15) * 512;
    #pragma unroll
    for (int ks = 0; ks < 16; ++ks) {
      const float* p = wrow + ks * 32 + quad * 8;
      float4 f0 = ((const float4*)p)[0];
      float4 f1 = ((const float4*)p)[1];
      short8 v;
      v[0] = (short)f2bf(f0.x); v[1] = (short)f2bf(f0.y);
      v[2] = (short)f2bf(f0.z); v[3] = (short)f2bf(f0.w);
      v[4] = (short)f2bf(f1.x); v[5] = (short)f2bf(f1.y);
      v[6] = (short)f2bf(f1.z); v[7] = (short)f2bf(f1.w);
      bfrag[ks] = v;
    }
  }

  // Gate-math ownership: thread -> (b = tid>>3, cols j0 = (tid&7)*2, j0+1).
  const int gb = tid >> 3;
  const int jp = tid & 7;
  float c0 = 0.f, c1 = 0.f;
  unsigned int* cnt = counters + bb * 32;   // 128B-spaced counters

  for (int t = 0; t < TDIM; ++t) {
    const unsigned short* hsrc = (t & 1) ? hbuf1 : hbuf0;
    unsigned short* hdst = (t & 1) ? hbuf0 : hbuf1;

    // Issue xg loads for this step early (independent of h; ~2000cyc slack
    // before the gate-math use). 4 coalesced dword loads per thread.
    const unsigned* xgu = (const unsigned*)(xg + (((size_t)t * 8 + bb) * 32 + jb) * 2048);
    unsigned ux0 = xgu[0 * 256 + tid];
    unsigned ux1 = xgu[1 * 256 + tid];
    unsigned ux2 = xgu[2 * 256 + tid];
    unsigned ux3 = xgu[3 * 256 + tid];

    // Stage h slice [32][512] bf16 (32 KB) from MALL via relaxed agent loads.
    const unsigned long long* src =
        (const unsigned long long*)hsrc + (size_t)bbase * 128;
    #pragma unroll
    for (int i = 0; i < 16; ++i) {
      int idx = i * 256 + tid;
      unsigned long long v = __hip_atomic_load(src + idx, __ATOMIC_RELAXED,
                                               __HIP_MEMORY_SCOPE_AGENT);
      *(unsigned long long*)&sH[idx >> 7][(idx & 127) * 4] = v;
    }
    __syncthreads();

    // G = Hslice @ Whh_slice^T : wave q does N-tile q, both M-tiles.
    f32x4 acc0 = {0.f,0.f,0.f,0.f}, acc1 = {0.f,0.f,0.f,0.f};
    #pragma unroll
    for (int ks = 0; ks < 16; ++ks) {
      int koff = ks * 32 + quad * 8;
      short8 a0 = *(const short8*)&sH[l15][koff];
      short8 a1 = *(const short8*)&sH[16 + l15][koff];
      acc0 = __builtin_amdgcn_mfma_f32_16x16x32_bf16(a0, bfrag[ks], acc0, 0, 0, 0);
      acc1 = __builtin_amdgcn_mfma_f32_16x16x32_bf16(a1, bfrag[ks], acc1, 0, 0, 0);
    }
    {
      int col = wave * 16 + l15;   // C/D: row=quad*4+reg, col=l15 (m89-verified)
      #pragma unroll
      for (int rr = 0; rr < 4; ++rr) {
        sG[quad * 4 + rr][col]      = acc0[rr];
        sG[16 + quad * 4 + rr][col] = acc1[rr];
      }
    }
    __syncthreads();

    // Gate math: thread owns (gb, j0) and (gb, j0+1).
    {
      int j0 = jp * 2;
      float gi0 = sG[gb][j0]          + bf2f((unsigned short)(ux0 & 0xffffu));
      float gi1 = sG[gb][j0 + 1]      + bf2f((unsigned short)(ux0 >> 16));
      float gf0 = sG[gb][16 + j0]     + bf2f((unsigned short)(ux1 & 0xffffu));
      float gf1 = sG[gb][16 + j0 + 1] + bf2f((unsigned short)(ux1 >> 16));
      float gg0 = sG[gb][32 + j0]     + bf2f((unsigned short)(ux2 & 0xffffu));
      float gg1 = sG[gb][32 + j0 + 1] + bf2f((unsigned short)(ux2 >> 16));
      float go0 = sG[gb][48 + j0]     + bf2f((unsigned short)(ux3 & 0xffffu));
      float go1 = sG[gb][48 + j0 + 1] + bf2f((unsigned short)(ux3 >> 16));

      c0 = sigmoidf_fast(gf0) * c0 + sigmoidf_fast(gi0) * tanhf_fast(gg0);
      c1 = sigmoidf_fast(gf1) * c1 + sigmoidf_fast(gi1) * tanhf_fast(gg1);
      float h0 = sigmoidf_fast(go0) * tanhf_fast(c0);
      float h1 = sigmoidf_fast(go1) * tanhf_fast(c1);
      unsigned hv = (unsigned)f2bf(h0) | ((unsigned)f2bf(h1) << 16);
      size_t hoff = (size_t)(bbase + gb) * 256 + (size_t)jb * 8 + jp;  // uints
      __hip_atomic_store((unsigned*)hdst + hoff, hv, __ATOMIC_RELAXED,
                         __HIP_MEMORY_SCOPE_AGENT);
    }

    // Sub-grid barrier over the 32 WGs of this batch block (relaxed only).
    // __syncthreads drains vmcnt(0) -> sc1 h-stores are at the coherence
    // point before tid0's counter increment becomes visible.
    __syncthreads();
    if (tid == 0) {
      __hip_atomic_fetch_add(cnt, 1u, __ATOMIC_RELAXED, __HIP_MEMORY_SCOPE_AGENT);
      const unsigned target = 32u * (unsigned)(t + 1);
      while (__hip_atomic_load(cnt, __ATOMIC_RELAXED, __HIP_MEMORY_SCOPE_AGENT) < target) {
        __builtin_amdgcn_s_sleep(1);
      }
    }
    __syncthreads();
  }
}

// ---------------------------------------------------------------------------
// Head: out[b] = h_last[b,:] . fc_w + fc_b
// ---------------------------------------------------------------------------
__global__ void head_kernel(const unsigned short* __restrict__ h,
                            const float* __restrict__ fc_w,
                            const float* __restrict__ fc_b,
                            float* __restrict__ out)
{
  const int b = blockIdx.x;
  const int lane = threadIdx.x;
  const unsigned short* hr = h + (size_t)b * 512;
  float s = 0.f;
  #pragma unroll
  for (int i = 0; i < 8; ++i) {
    int idx = lane + i * 64;
    s += bf2f(hr[idx]) * fc_w[idx];
  }
  #pragma unroll
  for (int off = 32; off > 0; off >>= 1) s += __shfl_down(s, off);
  if (lane == 0) out[b] = s + fc_b[0];
}

// ---------------------------------------------------------------------------
extern "C" void kernel_launch(void* const* d_in, const int* in_sizes, int n_in,
                              void* d_out, int out_size, void* d_ws, size_t ws_size,
                              hipStream_t stream) {
  const float* x    = (const float*)d_in[0];
  const float* W_ih = (const float*)d_in[1];
  const float* W_hh = (const float*)d_in[2];
  const float* b_ih = (const float*)d_in[3];
  const float* b_hh = (const float*)d_in[4];
  const float* fc_w = (const float*)d_in[5];
  const float* fc_b = (const float*)d_in[6];
  float* out = (float*)d_out;

  // Workspace layout (~269 MB):
  //   [0, 268435456)              xg bf16, scan-blocked layout
  //   [+0, +262144)               hbuf0 bf16 [256][512]
  //   [+262144, +524288)          hbuf1
  //   [+524288, +525312)          8 barrier counters, 128B apart
  const size_t XG_BYTES = (size_t)BDIM * TDIM * G4 * 2;  // 268435456
  const size_t HB_BYTES = (size_t)BDIM * HDIM * 2;       // 262144
  char* ws = (char*)d_ws;
  unsigned short* xg     = (unsigned short*)ws;
  unsigned short* hbuf0  = (unsigned short*)(ws + XG_BYTES);
  unsigned short* hbuf1  = (unsigned short*)(ws + XG_BYTES + HB_BYTES);
  unsigned int*   counters = (unsigned int*)(ws + XG_BYTES + 2 * HB_BYTES);

  // Zero h0 + counters (ws is poisoned 0xAA before every launch).
  hipMemsetAsync(ws + XG_BYTES, 0, 2 * HB_BYTES + 1024, stream);

  xg_gemm<<<dim3(16, 512), 256, 0, stream>>>(x, W_ih, b_ih, b_hh, xg);
  // grid=256 blocks, 1/CU (LDS 41.5KB, launch_bounds(256,1)) -> co-resident.
  lstm_scan<<<dim3(256), 256, 0, stream>>>(W_hh, xg, hbuf0, hbuf1, counters);
  // T=256 even: final write (t=255) went to hbuf0.
  head_kernel<<<dim3(BDIM), 64, 0, stream>>>(hbuf0, fc_w, fc_b, out);
}

// Round 3
// 1881.818 us; speedup vs baseline: 3.0593x; 1.2116x over previous
//
#include <hip/hip_runtime.h>

// Problem constants
#define BDIM 256   // batch
#define TDIM 256   // timesteps
#define IDIM 512   // input dim
#define HDIM 512   // hidden dim
#define G4   2048  // 4*H gate rows

typedef __attribute__((ext_vector_type(4))) float f32x4;
typedef __attribute__((ext_vector_type(8))) short short8;     // 8 bf16 MFMA frag
typedef __attribute__((ext_vector_type(8))) unsigned short u16x8;
typedef __attribute__((ext_vector_type(4))) unsigned short u16x4;

__device__ __forceinline__ unsigned short f2bf(float f) {
  union { float f; unsigned u; } v; v.f = f;
  unsigned r = v.u + 0x7FFFu + ((v.u >> 16) & 1u);   // RNE
  return (unsigned short)(r >> 16);
}
__device__ __forceinline__ float bf2f(unsigned short h) {
  union { unsigned u; float f; } v; v.u = ((unsigned)h) << 16; return v.f;
}
__device__ __forceinline__ float sigmoidf_fast(float x) {
  return 1.0f / (1.0f + __expf(-x));
}
__device__ __forceinline__ float tanhf_fast(float x) {
  float e = __expf(2.0f * x);
  return 1.0f - 2.0f / (e + 1.0f);
}
// async global->LDS 16B DMA (dst = wave-uniform base + lane*16)
__device__ __forceinline__ void gl_lds16(const unsigned short* g, unsigned short* l) {
  __builtin_amdgcn_global_load_lds(
      (const __attribute__((address_space(1))) unsigned int*)g,
      (__attribute__((address_space(3))) unsigned int*)l, 16, 0, 0);
}

// xg scatter offset shared by both GEMM epilogues.
// Layout: ((t*8 + bb)*8 + jw)*8192 + q*2048 + (b&31)*64 + jc
__device__ __forceinline__ size_t xg_off(int m, int n) {
  int b = m >> 8, t = m & 255;
  int q = n >> 9, jcol = n & 511;
  return (((size_t)t * 8 + (b >> 5)) * 8 + (jcol >> 6)) * 8192
         + (size_t)q * 2048 + (b & 31) * 64 + (jcol & 63);
}

// ---------------------------------------------------------------------------
// fp32 -> bf16 pre-convert of x (33.5M) and W_ih (1M). 8 elems/thread.
// ---------------------------------------------------------------------------
__global__ void __launch_bounds__(256) convert_bf16(
    const float* __restrict__ x, const float* __restrict__ w,
    unsigned short* __restrict__ xb, unsigned short* __restrict__ wb)
{
  const size_t NX8 = (size_t)BDIM * TDIM * IDIM / 8;   // 4194304
  const size_t NW8 = (size_t)G4 * IDIM / 8;            // 131072
  size_t idx = (size_t)blockIdx.x * 256 + threadIdx.x;
  const float4* sp; u16x8* dp; size_t i;
  if (idx < NX8)      { sp = (const float4*)x; dp = (u16x8*)xb; i = idx; }
  else if (idx < NX8 + NW8) { sp = (const float4*)w; dp = (u16x8*)wb; i = idx - NX8; }
  else return;
  float4 a = sp[i * 2], b = sp[i * 2 + 1];
  u16x8 o = { f2bf(a.x), f2bf(a.y), f2bf(a.z), f2bf(a.w),
              f2bf(b.x), f2bf(b.y), f2bf(b.z), f2bf(b.w) };
  dp[i] = o;
}

// ---------------------------------------------------------------------------
// Phase 1 (fast): m97-style bf16 GEMM, 128x128 tile, BK=32, global_load_lds 16B.
// LDS unpadded row-major [128][32] bf16 (DMA constraint); frag b128 reads are
// bank-uniform (8/bank = b128 floor) by construction.
// ---------------------------------------------------------------------------
__global__ void __launch_bounds__(256, 2) xg_gemm_bf16(
    const unsigned short* __restrict__ Xb, const unsigned short* __restrict__ Wb,
    const float* __restrict__ b_ih, const float* __restrict__ b_hh,
    unsigned short* __restrict__ xg)
{
  __shared__ unsigned short sA[128 * 32];
  __shared__ unsigned short sB[128 * 32];

  const int tid  = threadIdx.x;
  const int lane = tid & 63;
  const int wave = tid >> 6;
  const int l15  = lane & 15;
  const int quad = lane >> 4;
  const int nt = blockIdx.x & 15;
  const int mt = blockIdx.x >> 4;
  const int wm = (wave >> 1) * 64;
  const int wn = (wave & 1) * 64;

  f32x4 acc[4][4];
  #pragma unroll
  for (int i = 0; i < 4; ++i)
    #pragma unroll
    for (int j = 0; j < 4; ++j)
      acc[i][j] = (f32x4){0.f, 0.f, 0.f, 0.f};

  for (int kt = 0; kt < 16; ++kt) {
    // Stage A+B tiles: per wave 2+2 DMA issues of 1KB (64 lanes x 16B).
    #pragma unroll
    for (int i = 0; i < 2; ++i) {
      int c   = wave * 128 + i * 64 + lane;     // chunk id 0..511
      int row = c >> 2, cg = c & 3;
      const unsigned short* ga = Xb + (size_t)(mt * 128 + row) * 512 + kt * 32 + cg * 8;
      gl_lds16(ga, sA + (size_t)(wave * 128 + i * 64) * 8);
      const unsigned short* gb = Wb + (size_t)(nt * 128 + row) * 512 + kt * 32 + cg * 8;
      gl_lds16(gb, sB + (size_t)(wave * 128 + i * 64) * 8);
    }
    __syncthreads();   // drains vmcnt(0): DMA complete

    short8 af[4], bfr[4];
    #pragma unroll
    for (int i = 0; i < 4; ++i) {
      af[i]  = *(const short8*)&sA[(wm + i * 16 + l15) * 32 + quad * 8];
      bfr[i] = *(const short8*)&sB[(wn + i * 16 + l15) * 32 + quad * 8];
    }
    #pragma unroll
    for (int am = 0; am < 4; ++am)
      #pragma unroll
      for (int an = 0; an < 4; ++an)
        acc[am][an] = __builtin_amdgcn_mfma_f32_16x16x32_bf16(
            af[am], bfr[an], acc[am][an], 0, 0, 0);
    __syncthreads();
  }

  float biasv[4];
  #pragma unroll
  for (int an = 0; an < 4; ++an) {
    int n = nt * 128 + wn + an * 16 + l15;
    biasv[an] = b_ih[n] + b_hh[n];
  }
  #pragma unroll
  for (int am = 0; am < 4; ++am)
    #pragma unroll
    for (int reg = 0; reg < 4; ++reg) {
      int m = mt * 128 + wm + am * 16 + quad * 4 + reg;
      #pragma unroll
      for (int an = 0; an < 4; ++an) {
        int n = nt * 128 + wn + an * 16 + l15;
        xg[xg_off(m, n)] = f2bf(acc[am][an][reg] + biasv[an]);
      }
    }
}

// ---------------------------------------------------------------------------
// Phase 1 (fallback, ws too small): R2's fp32-staging GEMM, new epilogue.
// ---------------------------------------------------------------------------
__global__ void __launch_bounds__(256, 2) xg_gemm_f32(
    const float* __restrict__ X, const float* __restrict__ Wih,
    const float* __restrict__ b_ih, const float* __restrict__ b_hh,
    unsigned short* __restrict__ xg)
{
  __shared__ unsigned short sA[128][40];
  __shared__ unsigned short sB[128][40];

  const int tid  = threadIdx.x;
  const int lane = tid & 63;
  const int wave = tid >> 6;
  const int l15  = lane & 15;
  const int quad = lane >> 4;
  const int nt = blockIdx.x;
  const int mt = blockIdx.y;
  const int wm = (wave >> 1) * 64;
  const int wn = (wave & 1) * 64;
  const int r    = tid >> 1;
  const int half = (tid & 1) * 16;

  const float* arow = X   + (size_t)(mt * 128 + r) * 512 + half;
  const float* brow = Wih + (size_t)(nt * 128 + r) * 512 + half;

  f32x4 acc[4][4];
  #pragma unroll
  for (int i = 0; i < 4; ++i)
    #pragma unroll
    for (int j = 0; j < 4; ++j)
      acc[i][j] = (f32x4){0.f, 0.f, 0.f, 0.f};

  for (int kt = 0; kt < 16; ++kt) {
    const float* ap = arow + kt * 32;
    const float* bp = brow + kt * 32;
    #pragma unroll
    for (int i = 0; i < 4; ++i) {
      float4 a = ((const float4*)ap)[i];
      u16x4 av = { f2bf(a.x), f2bf(a.y), f2bf(a.z), f2bf(a.w) };
      *(u16x4*)&sA[r][half + i * 4] = av;
      float4 b = ((const float4*)bp)[i];
      u16x4 bv = { f2bf(b.x), f2bf(b.y), f2bf(b.z), f2bf(b.w) };
      *(u16x4*)&sB[r][half + i * 4] = bv;
    }
    __syncthreads();
    short8 af[4], bfr[4];
    #pragma unroll
    for (int i = 0; i < 4; ++i) {
      af[i]  = *(const short8*)&sA[wm + i * 16 + l15][quad * 8];
      bfr[i] = *(const short8*)&sB[wn + i * 16 + l15][quad * 8];
    }
    #pragma unroll
    for (int am = 0; am < 4; ++am)
      #pragma unroll
      for (int an = 0; an < 4; ++an)
        acc[am][an] = __builtin_amdgcn_mfma_f32_16x16x32_bf16(
            af[am], bfr[an], acc[am][an], 0, 0, 0);
    __syncthreads();
  }

  float biasv[4];
  #pragma unroll
  for (int an = 0; an < 4; ++an) {
    int n = nt * 128 + wn + an * 16 + l15;
    biasv[an] = b_ih[n] + b_hh[n];
  }
  #pragma unroll
  for (int am = 0; am < 4; ++am)
    #pragma unroll
    for (int reg = 0; reg < 4; ++reg) {
      int m = mt * 128 + wm + am * 16 + quad * 4 + reg;
      #pragma unroll
      for (int an = 0; an < 4; ++an) {
        int n = nt * 128 + wn + an * 16 + l15;
        xg[xg_off(m, n)] = f2bf(acc[am][an][reg] + biasv[an]);
      }
    }
}

// ---------------------------------------------------------------------------
// Phase 2: persistent scan. 64 WGs x 512 thr. WG (bb,jw): batch rows bb*32..+32,
// h-cols jw*64..+64 (gate rows q*512+jw*64+j). Wave w: gate q=w>>1, n-subtiles
// (w&1)*2..+1. W_hh frags: 128 VGPR/lane, loaded once. c[4] in registers.
// h via relaxed agent (sc1/MALL) atomics. Barrier: 8 per-WG FLAG STORES (no
// RMW serialization) + 8-lane vector poll per wave (no extra __syncthreads).
// ---------------------------------------------------------------------------
__global__ void __launch_bounds__(512, 2) lstm_scan(
    const float* __restrict__ Whh, const unsigned short* __restrict__ xg,
    unsigned short* __restrict__ hbuf0, unsigned short* __restrict__ hbuf1,
    unsigned int* __restrict__ flags)
{
  __shared__ unsigned short sH[32][520];   // h slice, +8 pad (frag reads: 8/bank floor)
  __shared__ float sG[32][260];            // gates, +4 pad (reads/writes <=2-way)

  const int tid  = threadIdx.x;
  const int lane = tid & 63;
  const int wave = tid >> 6;        // 0..7
  const int l15  = lane & 15;
  const int quad = lane >> 4;
  const int q    = wave >> 1;       // gate (i,f,g,o)
  const int np   = (wave & 1) * 2;  // n-subtile pair
  const int bb = blockIdx.x >> 3;   // batch block 0..7
  const int jw = blockIdx.x & 7;    // col block 0..7
  const int bbase = bb * 32;
  const int jbase = jw * 64;

  // One-time: W_hh -> 2x16 register B-frags per lane (128 VGPRs).
  short8 bfrag[2][16];
  #pragma unroll
  for (int n2 = 0; n2 < 2; ++n2) {
    const float* wrow = Whh + (size_t)(q * 512 + jbase + (np + n2) * 16 + l15) * 512;
    #pragma unroll
    for (int ks = 0; ks < 16; ++ks) {
      const float* p = wrow + ks * 32 + quad * 8;
      float4 f0 = ((const float4*)p)[0];
      float4 f1 = ((const float4*)p)[1];
      short8 v;
      v[0] = (short)f2bf(f0.x); v[1] = (short)f2bf(f0.y);
      v[2] = (short)f2bf(f0.z); v[3] = (short)f2bf(f0.w);
      v[4] = (short)f2bf(f1.x); v[5] = (short)f2bf(f1.y);
      v[6] = (short)f2bf(f1.z); v[7] = (short)f2bf(f1.w);
      bfrag[n2][ks] = v;
    }
  }

  // Gate-math ownership: thread -> row r = tid>>4 (0..31), cols j0..j0+3.
  const int r  = tid >> 4;
  const int j0 = (tid & 15) * 4;
  float c[4] = {0.f, 0.f, 0.f, 0.f};
  unsigned int* flagp = flags + bb * 32;   // flags[bb][0..7], 128B/bb

  for (int t = 0; t < TDIM; ++t) {
    const unsigned short* hsrc = (t & 1) ? hbuf1 : hbuf0;
    unsigned short* hdst = (t & 1) ? hbuf0 : hbuf1;

    // xg prefetch (independent of flags; used ~2k cycles later).
    const unsigned short* xgb = xg + (((size_t)t * 8 + bb) * 8 + jw) * 8192;
    u16x4 xv[4];
    #pragma unroll
    for (int qq = 0; qq < 4; ++qq)
      xv[qq] = *(const u16x4*)(xgb + qq * 2048 + r * 64 + j0);

    // Poll: need all 8 producer flags of this bb >= t. Every wave polls
    // (no barrier needed before staging). Flag stores are monotonic.
    if (t > 0) {
      const unsigned int* fp = flagp + (lane & 7);
      for (;;) {
        unsigned v = __hip_atomic_load(fp, __ATOMIC_RELAXED, __HIP_MEMORY_SCOPE_AGENT);
        bool ok = (lane >= 8) || (v >= (unsigned)t);
        if ((__ballot(ok) & 0xFFull) == 0xFFull) break;
      }
    }

    // Stage h slice [32][512] bf16 (32 KB) from MALL.
    const unsigned long long* src =
        (const unsigned long long*)hsrc + (size_t)bbase * 128;
    #pragma unroll
    for (int i = 0; i < 8; ++i) {
      int idx = i * 512 + tid;
      unsigned long long v = __hip_atomic_load(src + idx, __ATOMIC_RELAXED,
                                               __HIP_MEMORY_SCOPE_AGENT);
      *(unsigned long long*)&sH[idx >> 7][(idx & 127) * 4] = v;
    }
    __syncthreads();

    // G-tile: 2 m-subtiles x 2 n-subtiles, K=512.
    f32x4 acc[2][2];
    acc[0][0] = acc[0][1] = acc[1][0] = acc[1][1] = (f32x4){0.f,0.f,0.f,0.f};
    #pragma unroll
    for (int ks = 0; ks < 16; ++ks) {
      int koff = ks * 32 + quad * 8;
      short8 a0 = *(const short8*)&sH[l15][koff];
      short8 a1 = *(const short8*)&sH[16 + l15][koff];
      acc[0][0] = __builtin_amdgcn_mfma_f32_16x16x32_bf16(a0, bfrag[0][ks], acc[0][0], 0, 0, 0);
      acc[1][0] = __builtin_amdgcn_mfma_f32_16x16x32_bf16(a1, bfrag[0][ks], acc[1][0], 0, 0, 0);
      acc[0][1] = __builtin_amdgcn_mfma_f32_16x16x32_bf16(a0, bfrag[1][ks], acc[0][1], 0, 0, 0);
      acc[1][1] = __builtin_amdgcn_mfma_f32_16x16x32_bf16(a1, bfrag[1][ks], acc[1][1], 0, 0, 0);
    }
    #pragma unroll
    for (int m = 0; m < 2; ++m)
      #pragma unroll
      for (int n2 = 0; n2 < 2; ++n2) {
        int col = q * 64 + (np + n2) * 16 + l15;
        #pragma unroll
        for (int rr = 0; rr < 4; ++rr)
          sG[m * 16 + quad * 4 + rr][col] = acc[m][n2][rr];
      }
    __syncthreads();

    // Gate math: 4 cells (r, j0..j0+3).
    {
      float4 GI = *(const float4*)&sG[r][j0];
      float4 GF = *(const float4*)&sG[r][64 + j0];
      float4 GG = *(const float4*)&sG[r][128 + j0];
      float4 GO = *(const float4*)&sG[r][192 + j0];
      float h4[4];
      float gi[4] = {GI.x, GI.y, GI.z, GI.w};
      float gf[4] = {GF.x, GF.y, GF.z, GF.w};
      float gg[4] = {GG.x, GG.y, GG.z, GG.w};
      float go[4] = {GO.x, GO.y, GO.z, GO.w};
      #pragma unroll
      for (int k = 0; k < 4; ++k) {
        float vi = sigmoidf_fast(gi[k] + bf2f(xv[0][k]));
        float vf = sigmoidf_fast(gf[k] + bf2f(xv[1][k]));
        float vg = tanhf_fast   (gg[k] + bf2f(xv[2][k]));
        float vo = sigmoidf_fast(go[k] + bf2f(xv[3][k]));
        c[k] = vf * c[k] + vi * vg;
        h4[k] = vo * tanhf_fast(c[k]);
      }
      unsigned long long hv =
          (unsigned long long)f2bf(h4[0])
        | ((unsigned long long)f2bf(h4[1]) << 16)
        | ((unsigned long long)f2bf(h4[2]) << 32)
        | ((unsigned long long)f2bf(h4[3]) << 48);
      size_t hoff = (size_t)(bbase + r) * 128 + (jbase + j0) / 4;  // in ulls
      __hip_atomic_store((unsigned long long*)hdst + hoff, hv, __ATOMIC_RELAXED,
                         __HIP_MEMORY_SCOPE_AGENT);
    }

    // Release: syncthreads drains vmcnt(0) per wave -> all h stores at MALL;
    // then one plain relaxed flag store (no RMW).
    __syncthreads();
    if (tid == 0)
      __hip_atomic_store(flagp + jw, (unsigned)(t + 1), __ATOMIC_RELAXED,
                         __HIP_MEMORY_SCOPE_AGENT);
  }
}

// ---------------------------------------------------------------------------
// Head: out[b] = h_last[b,:] . fc_w + fc_b
// ---------------------------------------------------------------------------
__global__ void head_kernel(const unsigned short* __restrict__ h,
                            const float* __restrict__ fc_w,
                            const float* __restrict__ fc_b,
                            float* __restrict__ out)
{
  const int b = blockIdx.x;
  const int lane = threadIdx.x;
  const unsigned short* hr = h + (size_t)b * 512;
  float s = 0.f;
  #pragma unroll
  for (int i = 0; i < 8; ++i) {
    int idx = lane + i * 64;
    s += bf2f(hr[idx]) * fc_w[idx];
  }
  #pragma unroll
  for (int off = 32; off > 0; off >>= 1) s += __shfl_down(s, off);
  if (lane == 0) out[b] = s + fc_b[0];
}

// ---------------------------------------------------------------------------
extern "C" void kernel_launch(void* const* d_in, const int* in_sizes, int n_in,
                              void* d_out, int out_size, void* d_ws, size_t ws_size,
                              hipStream_t stream) {
  const float* x    = (const float*)d_in[0];
  const float* W_ih = (const float*)d_in[1];
  const float* W_hh = (const float*)d_in[2];
  const float* b_ih = (const float*)d_in[3];
  const float* b_hh = (const float*)d_in[4];
  const float* fc_w = (const float*)d_in[5];
  const float* fc_b = (const float*)d_in[6];
  float* out = (float*)d_out;

  // Workspace layout:
  //   [0, 268435456)   xg bf16 (scan-blocked)
  //   + hbuf0 (256KB), hbuf1 (256KB), flags (4KB)
  //   [fast path only] xb bf16 (64MB), wb bf16 (2MB)
  const size_t XG = (size_t)BDIM * TDIM * G4 * 2;   // 268435456
  const size_t HB = (size_t)BDIM * HDIM * 2;        // 262144
  char* ws = (char*)d_ws;
  unsigned short* xg    = (unsigned short*)ws;
  unsigned short* hbuf0 = (unsigned short*)(ws + XG);
  unsigned short* hbuf1 = (unsigned short*)(ws + XG + HB);
  unsigned int*   flags = (unsigned int*)(ws + XG + 2 * HB);
  const size_t XB_OFF = XG + 2 * HB + 4096;
  const size_t WB_OFF = XB_OFF + (size_t)BDIM * TDIM * IDIM * 2;  // +64MB
  const size_t NEED   = WB_OFF + (size_t)G4 * IDIM * 2;           // +2MB

  // Zero h0 + flags (ws poisoned 0xAA each call; flags MUST start 0).
  hipMemsetAsync(ws + XG, 0, 2 * HB + 4096, stream);

  if (ws_size >= NEED) {
    unsigned short* xb = (unsigned short*)(ws + XB_OFF);
    unsigned short* wb = (unsigned short*)(ws + WB_OFF);
    convert_bf16<<<16896, 256, 0, stream>>>(x, W_ih, xb, wb);
    xg_gemm_bf16<<<8192, 256, 0, stream>>>(xb, wb, b_ih, b_hh, xg);
  } else {
    xg_gemm_f32<<<dim3(16, 512), 256, 0, stream>>>(x, W_ih, b_ih, b_hh, xg);
  }
  // 64 WGs (8 bb x 8 jw) x 512 thr, co-resident trivially.
  lstm_scan<<<64, 512, 0, stream>>>(W_hh, xg, hbuf0, hbuf1, flags);
  // T=256 even: final write (t=255, odd) went to hbuf0.
  head_kernel<<<BDIM, 64, 0, stream>>>(hbuf0, fc_w, fc_b, out);
}

// Round 6
// 1522.277 us; speedup vs baseline: 3.7818x; 1.2362x over previous
//
#include <hip/hip_runtime.h>

// Problem constants
#define BDIM 256   // batch
#define TDIM 256   // timesteps
#define IDIM 512   // input dim
#define HDIM 512   // hidden dim
#define G4   2048  // 4*H gate rows

typedef __attribute__((ext_vector_type(4))) float f32x4;
typedef __attribute__((ext_vector_type(8))) short short8;     // 8 bf16 MFMA frag
typedef __attribute__((ext_vector_type(8))) unsigned short u16x8;
typedef __attribute__((ext_vector_type(4))) unsigned short u16x4;
typedef unsigned long long ull;

__device__ __forceinline__ unsigned short f2bf(float f) {
  union { float f; unsigned u; } v; v.f = f;
  unsigned r = v.u + 0x7FFFu + ((v.u >> 16) & 1u);   // RNE
  return (unsigned short)(r >> 16);
}
__device__ __forceinline__ float bf2f(unsigned short h) {
  union { unsigned u; float f; } v; v.u = ((unsigned)h) << 16; return v.f;
}
__device__ __forceinline__ float sigmoidf_fast(float x) {
  return 1.0f / (1.0f + __expf(-x));
}
__device__ __forceinline__ float tanhf_fast(float x) {
  float e = __expf(2.0f * x);
  return 1.0f - 2.0f / (e + 1.0f);
}
// async global->LDS 16B DMA (dst = wave-uniform base + lane*16)
__device__ __forceinline__ void gl_lds16(const unsigned short* g, unsigned short* l) {
  __builtin_amdgcn_global_load_lds(
      (const __attribute__((address_space(1))) unsigned int*)g,
      (__attribute__((address_space(3))) unsigned int*)l, 16, 0, 0);
}

// xg scatter offset shared by both GEMM epilogues.
// Layout: ((t*8 + bb)*8 + jw)*8192 + q*2048 + (b&31)*64 + jc
__device__ __forceinline__ size_t xg_off(int m, int n) {
  int b = m >> 8, t = m & 255;
  int q = n >> 9, jcol = n & 511;
  return (((size_t)t * 8 + (b >> 5)) * 8 + (jcol >> 6)) * 8192
         + (size_t)q * 2048 + (b & 31) * 64 + (jcol & 63);
}

// ---------------------------------------------------------------------------
// fp32 -> bf16 pre-convert of x (33.5M) and W_ih (1M). 8 elems/thread.
// ---------------------------------------------------------------------------
__global__ void __launch_bounds__(256) convert_bf16(
    const float* __restrict__ x, const float* __restrict__ w,
    unsigned short* __restrict__ xb, unsigned short* __restrict__ wb)
{
  const size_t NX8 = (size_t)BDIM * TDIM * IDIM / 8;   // 4194304
  const size_t NW8 = (size_t)G4 * IDIM / 8;            // 131072
  size_t idx = (size_t)blockIdx.x * 256 + threadIdx.x;
  const float4* sp; u16x8* dp; size_t i;
  if (idx < NX8)      { sp = (const float4*)x; dp = (u16x8*)xb; i = idx; }
  else if (idx < NX8 + NW8) { sp = (const float4*)w; dp = (u16x8*)wb; i = idx - NX8; }
  else return;
  float4 a = sp[i * 2], b = sp[i * 2 + 1];
  u16x8 o = { f2bf(a.x), f2bf(a.y), f2bf(a.z), f2bf(a.w),
              f2bf(b.x), f2bf(b.y), f2bf(b.z), f2bf(b.w) };
  dp[i] = o;
}

// ---------------------------------------------------------------------------
// Phase 1 (fast): m97-style bf16 GEMM, 128x128 tile, BK=32, global_load_lds 16B.
// ---------------------------------------------------------------------------
__global__ void __launch_bounds__(256, 2) xg_gemm_bf16(
    const unsigned short* __restrict__ Xb, const unsigned short* __restrict__ Wb,
    const float* __restrict__ b_ih, const float* __restrict__ b_hh,
    unsigned short* __restrict__ xg)
{
  __shared__ unsigned short sA[128 * 32];
  __shared__ unsigned short sB[128 * 32];

  const int tid  = threadIdx.x;
  const int lane = tid & 63;
  const int wave = tid >> 6;
  const int l15  = lane & 15;
  const int quad = lane >> 4;
  const int nt = blockIdx.x & 15;
  const int mt = blockIdx.x >> 4;
  const int wm = (wave >> 1) * 64;
  const int wn = (wave & 1) * 64;

  f32x4 acc[4][4];
  #pragma unroll
  for (int i = 0; i < 4; ++i)
    #pragma unroll
    for (int j = 0; j < 4; ++j)
      acc[i][j] = (f32x4){0.f, 0.f, 0.f, 0.f};

  for (int kt = 0; kt < 16; ++kt) {
    #pragma unroll
    for (int i = 0; i < 2; ++i) {
      int c   = wave * 128 + i * 64 + lane;
      int row = c >> 2, cg = c & 3;
      const unsigned short* ga = Xb + (size_t)(mt * 128 + row) * 512 + kt * 32 + cg * 8;
      gl_lds16(ga, sA + (size_t)(wave * 128 + i * 64) * 8);
      const unsigned short* gb = Wb + (size_t)(nt * 128 + row) * 512 + kt * 32 + cg * 8;
      gl_lds16(gb, sB + (size_t)(wave * 128 + i * 64) * 8);
    }
    __syncthreads();

    short8 af[4], bfr[4];
    #pragma unroll
    for (int i = 0; i < 4; ++i) {
      af[i]  = *(const short8*)&sA[(wm + i * 16 + l15) * 32 + quad * 8];
      bfr[i] = *(const short8*)&sB[(wn + i * 16 + l15) * 32 + quad * 8];
    }
    #pragma unroll
    for (int am = 0; am < 4; ++am)
      #pragma unroll
      for (int an = 0; an < 4; ++an)
        acc[am][an] = __builtin_amdgcn_mfma_f32_16x16x32_bf16(
            af[am], bfr[an], acc[am][an], 0, 0, 0);
    __syncthreads();
  }

  float biasv[4];
  #pragma unroll
  for (int an = 0; an < 4; ++an) {
    int n = nt * 128 + wn + an * 16 + l15;
    biasv[an] = b_ih[n] + b_hh[n];
  }
  #pragma unroll
  for (int am = 0; am < 4; ++am)
    #pragma unroll
    for (int reg = 0; reg < 4; ++reg) {
      int m = mt * 128 + wm + am * 16 + quad * 4 + reg;
      #pragma unroll
      for (int an = 0; an < 4; ++an) {
        int n = nt * 128 + wn + an * 16 + l15;
        xg[xg_off(m, n)] = f2bf(acc[am][an][reg] + biasv[an]);
      }
    }
}

// ---------------------------------------------------------------------------
// Phase 1 (fallback, ws too small): fp32-staging GEMM.
// ---------------------------------------------------------------------------
__global__ void __launch_bounds__(256, 2) xg_gemm_f32(
    const float* __restrict__ X, const float* __restrict__ Wih,
    const float* __restrict__ b_ih, const float* __restrict__ b_hh,
    unsigned short* __restrict__ xg)
{
  __shared__ unsigned short sA[128][40];
  __shared__ unsigned short sB[128][40];

  const int tid  = threadIdx.x;
  const int lane = tid & 63;
  const int wave = tid >> 6;
  const int l15  = lane & 15;
  const int quad = lane >> 4;
  const int nt = blockIdx.x;
  const int mt = blockIdx.y;
  const int wm = (wave >> 1) * 64;
  const int wn = (wave & 1) * 64;
  const int r    = tid >> 1;
  const int half = (tid & 1) * 16;

  const float* arow = X   + (size_t)(mt * 128 + r) * 512 + half;
  const float* brow = Wih + (size_t)(nt * 128 + r) * 512 + half;

  f32x4 acc[4][4];
  #pragma unroll
  for (int i = 0; i < 4; ++i)
    #pragma unroll
    for (int j = 0; j < 4; ++j)
      acc[i][j] = (f32x4){0.f, 0.f, 0.f, 0.f};

  for (int kt = 0; kt < 16; ++kt) {
    const float* ap = arow + kt * 32;
    const float* bp = brow + kt * 32;
    #pragma unroll
    for (int i = 0; i < 4; ++i) {
      float4 a = ((const float4*)ap)[i];
      u16x4 av = { f2bf(a.x), f2bf(a.y), f2bf(a.z), f2bf(a.w) };
      *(u16x4*)&sA[r][half + i * 4] = av;
      float4 b = ((const float4*)bp)[i];
      u16x4 bv = { f2bf(b.x), f2bf(b.y), f2bf(b.z), f2bf(b.w) };
      *(u16x4*)&sB[r][half + i * 4] = bv;
    }
    __syncthreads();
    short8 af[4], bfr[4];
    #pragma unroll
    for (int i = 0; i < 4; ++i) {
      af[i]  = *(const short8*)&sA[wm + i * 16 + l15][quad * 8];
      bfr[i] = *(const short8*)&sB[wn + i * 16 + l15][quad * 8];
    }
    #pragma unroll
    for (int am = 0; am < 4; ++am)
      #pragma unroll
      for (int an = 0; an < 4; ++an)
        acc[am][an] = __builtin_amdgcn_mfma_f32_16x16x32_bf16(
            af[am], bfr[an], acc[am][an], 0, 0, 0);
    __syncthreads();
  }

  float biasv[4];
  #pragma unroll
  for (int an = 0; an < 4; ++an) {
    int n = nt * 128 + wn + an * 16 + l15;
    biasv[an] = b_ih[n] + b_hh[n];
  }
  #pragma unroll
  for (int am = 0; am < 4; ++am)
    #pragma unroll
    for (int reg = 0; reg < 4; ++reg) {
      int m = mt * 128 + wm + am * 16 + quad * 4 + reg;
      #pragma unroll
      for (int an = 0; an < 4; ++an) {
        int n = nt * 128 + wn + an * 16 + l15;
        xg[xg_off(m, n)] = f2bf(acc[am][an][reg] + biasv[an]);
      }
    }
}

// ---------------------------------------------------------------------------
// Phase 2: persistent scan (R3 structure + contention fixes; R5 bug fixed).
// 64 WGs x 512 thr. WG (bb,jw): batch rows bb*32..+32, h-cols jw*64..+64.
// W_hh frags in regs (128 VGPR). h + flags via relaxed agent-scope atomics
// (MALL-coherent). vs R3:
//  - wave0-only poll (64 pollers not 512) + s_sleep throttle + bounded guard
//  - h staging loads clustered into registers before LDS writes
//  - xg loads issued at the very top of the step
// R5 BUG FIX: staging base is bbase*128 ulls (row = 512 bf16 = 128 ulls);
// R5 had bbase*64 -> staged wrong batch rows for bb>0.
// ---------------------------------------------------------------------------
__global__ void __launch_bounds__(512, 2) lstm_scan(
    const float* __restrict__ Whh, const unsigned short* __restrict__ xg,
    unsigned short* __restrict__ hbuf0, unsigned short* __restrict__ hbuf1,
    unsigned int* __restrict__ flags)
{
  __shared__ unsigned short sH[32][520];   // h slice, +8 pad
  __shared__ float sG[32][260];            // gates, +4 pad

  const int tid  = threadIdx.x;
  const int lane = tid & 63;
  const int wave = tid >> 6;        // 0..7
  const int l15  = lane & 15;
  const int quad = lane >> 4;
  const int q    = wave >> 1;       // gate (i,f,g,o)
  const int np   = (wave & 1) * 2;  // n-subtile pair
  const int bb = blockIdx.x >> 3;   // batch block 0..7
  const int jw = blockIdx.x & 7;    // col block 0..7
  const int bbase = bb * 32;
  const int jbase = jw * 64;

  // One-time: W_hh -> 2x16 register B-frags per lane (128 VGPRs).
  short8 bfrag[2][16];
  #pragma unroll
  for (int n2 = 0; n2 < 2; ++n2) {
    const float* wrow = Whh + (size_t)(q * 512 + jbase + (np + n2) * 16 + l15) * 512;
    #pragma unroll
    for (int ks = 0; ks < 16; ++ks) {
      const float* p = wrow + ks * 32 + quad * 8;
      float4 f0 = ((const float4*)p)[0];
      float4 f1 = ((const float4*)p)[1];
      short8 v;
      v[0] = (short)f2bf(f0.x); v[1] = (short)f2bf(f0.y);
      v[2] = (short)f2bf(f0.z); v[3] = (short)f2bf(f0.w);
      v[4] = (short)f2bf(f1.x); v[5] = (short)f2bf(f1.y);
      v[6] = (short)f2bf(f1.z); v[7] = (short)f2bf(f1.w);
      bfrag[n2][ks] = v;
    }
  }

  const int r  = tid >> 4;          // gate-math row 0..31
  const int j0 = (tid & 15) * 4;    // gate-math col group
  float c[4] = {0.f, 0.f, 0.f, 0.f};
  unsigned int* flagbase = flags + bb * 32;   // 8 flags/group, 128B apart

  for (int t = 0; t < TDIM; ++t) {
    const unsigned short* hsrc = (t & 1) ? hbuf1 : hbuf0;
    unsigned short* hdst = (t & 1) ? hbuf0 : hbuf1;

    // xg loads for step t (plain cached; in flight across poll + staging).
    const unsigned short* xgb = xg + (((size_t)t * 8 + bb) * 8 + jw) * 8192;
    ull xv64[4];
    #pragma unroll
    for (int qq = 0; qq < 4; ++qq)
      xv64[qq] = *(const ull*)(xgb + qq * 2048 + r * 64 + j0);

    // Poll (wave 0 only): all 8 producer-WG flags of this bb >= t.
    if (t > 0 && wave == 0) {
      const unsigned int* fp = flagbase + (lane & 7);
      int guard = 0;
      for (;;) {
        unsigned v = __hip_atomic_load(fp, __ATOMIC_RELAXED, __HIP_MEMORY_SCOPE_AGENT);
        bool ok = (lane >= 8) || (v >= (unsigned)t);
        if ((__ballot(ok) & 0xFFull) == 0xFFull) break;
        if (++guard > (1 << 21)) break;   // safety valve: never hit when correct
        __builtin_amdgcn_s_sleep(1);
      }
    }
    __syncthreads();   // (a) release WG after poll

    // Stage h slice [32][512] bf16 (32 KB): cluster 8 loads, then LDS writes.
    // Row stride = 512 bf16 = 128 ulls  ->  base = bbase*128  (R5 bug: *64).
    const ull* src = (const ull*)hsrc + (size_t)bbase * 128;
    ull hv[8];
    #pragma unroll
    for (int i = 0; i < 8; ++i)
      hv[i] = __hip_atomic_load(src + i * 512 + tid, __ATOMIC_RELAXED,
                                __HIP_MEMORY_SCOPE_AGENT);
    #pragma unroll
    for (int i = 0; i < 8; ++i) {
      int idx = i * 512 + tid;
      *(ull*)&sH[idx >> 7][(idx & 127) * 4] = hv[i];
    }
    __syncthreads();   // (b)

    // G-tile MFMA: 2 m-subtiles x 2 n-subtiles, K=512.
    f32x4 acc[2][2];
    acc[0][0] = acc[0][1] = acc[1][0] = acc[1][1] = (f32x4){0.f,0.f,0.f,0.f};
    #pragma unroll
    for (int ks = 0; ks < 16; ++ks) {
      int koff = ks * 32 + quad * 8;
      short8 a0 = *(const short8*)&sH[l15][koff];
      short8 a1 = *(const short8*)&sH[16 + l15][koff];
      acc[0][0] = __builtin_amdgcn_mfma_f32_16x16x32_bf16(a0, bfrag[0][ks], acc[0][0], 0, 0, 0);
      acc[1][0] = __builtin_amdgcn_mfma_f32_16x16x32_bf16(a1, bfrag[0][ks], acc[1][0], 0, 0, 0);
      acc[0][1] = __builtin_amdgcn_mfma_f32_16x16x32_bf16(a0, bfrag[1][ks], acc[0][1], 0, 0, 0);
      acc[1][1] = __builtin_amdgcn_mfma_f32_16x16x32_bf16(a1, bfrag[1][ks], acc[1][1], 0, 0, 0);
    }
    #pragma unroll
    for (int m = 0; m < 2; ++m)
      #pragma unroll
      for (int n2 = 0; n2 < 2; ++n2) {
        int col = q * 64 + (np + n2) * 16 + l15;
        #pragma unroll
        for (int rr = 0; rr < 4; ++rr)
          sG[m * 16 + quad * 4 + rr][col] = acc[m][n2][rr];
      }
    __syncthreads();   // (c)

    // Gate math: 4 cells (r, j0..j0+3). xg arrived long ago (drained at (b)).
    {
      float4 GI = *(const float4*)&sG[r][j0];
      float4 GF = *(const float4*)&sG[r][64 + j0];
      float4 GG = *(const float4*)&sG[r][128 + j0];
      float4 GO = *(const float4*)&sG[r][192 + j0];
      u16x4 xi  = __builtin_bit_cast(u16x4, xv64[0]);
      u16x4 xf  = __builtin_bit_cast(u16x4, xv64[1]);
      u16x4 xgv = __builtin_bit_cast(u16x4, xv64[2]);
      u16x4 xo  = __builtin_bit_cast(u16x4, xv64[3]);
      float gi[4] = {GI.x, GI.y, GI.z, GI.w};
      float gf[4] = {GF.x, GF.y, GF.z, GF.w};
      float gg[4] = {GG.x, GG.y, GG.z, GG.w};
      float go[4] = {GO.x, GO.y, GO.z, GO.w};
      float h4[4];
      #pragma unroll
      for (int k = 0; k < 4; ++k) {
        float vi = sigmoidf_fast(gi[k] + bf2f(xi[k]));
        float vf = sigmoidf_fast(gf[k] + bf2f(xf[k]));
        float vg = tanhf_fast   (gg[k] + bf2f(xgv[k]));
        float vo = sigmoidf_fast(go[k] + bf2f(xo[k]));
        c[k] = vf * c[k] + vi * vg;
        h4[k] = vo * tanhf_fast(c[k]);
      }
      ull hvout = (ull)f2bf(h4[0])
                | ((ull)f2bf(h4[1]) << 16)
                | ((ull)f2bf(h4[2]) << 32)
                | ((ull)f2bf(h4[3]) << 48);
      __hip_atomic_store((ull*)hdst + (size_t)(bbase + r) * 128 + (jbase + j0) / 4,
                         hvout, __ATOMIC_RELAXED, __HIP_MEMORY_SCOPE_AGENT);
    }

    // (d) drains vmcnt(0): all h-stores of this WG acked at MALL, then flag.
    __syncthreads();
    if (tid == 0)
      __hip_atomic_store(flagbase + jw, (unsigned)(t + 1), __ATOMIC_RELAXED,
                         __HIP_MEMORY_SCOPE_AGENT);
  }
}

// ---------------------------------------------------------------------------
// Head: out[b] = h_last[b,:] . fc_w + fc_b
// ---------------------------------------------------------------------------
__global__ void head_kernel(const unsigned short* __restrict__ h,
                            const float* __restrict__ fc_w,
                            const float* __restrict__ fc_b,
                            float* __restrict__ out)
{
  const int b = blockIdx.x;
  const int lane = threadIdx.x;
  const unsigned short* hr = h + (size_t)b * 512;
  float s = 0.f;
  #pragma unroll
  for (int i = 0; i < 8; ++i) {
    int idx = lane + i * 64;
    s += bf2f(hr[idx]) * fc_w[idx];
  }
  #pragma unroll
  for (int off = 32; off > 0; off >>= 1) s += __shfl_down(s, off);
  if (lane == 0) out[b] = s + fc_b[0];
}

// ---------------------------------------------------------------------------
extern "C" void kernel_launch(void* const* d_in, const int* in_sizes, int n_in,
                              void* d_out, int out_size, void* d_ws, size_t ws_size,
                              hipStream_t stream) {
  const float* x    = (const float*)d_in[0];
  const float* W_ih = (const float*)d_in[1];
  const float* W_hh = (const float*)d_in[2];
  const float* b_ih = (const float*)d_in[3];
  const float* b_hh = (const float*)d_in[4];
  const float* fc_w = (const float*)d_in[5];
  const float* fc_b = (const float*)d_in[6];
  float* out = (float*)d_out;

  // Workspace layout:
  //   [0, 268435456)   xg bf16 (scan-blocked)
  //   + hbuf0 (256KB), hbuf1 (256KB), flags (4KB)
  //   [fast GEMM only] xb bf16 (64MB), wb bf16 (2MB)
  const size_t XG = (size_t)BDIM * TDIM * G4 * 2;   // 268435456
  const size_t HB = (size_t)BDIM * HDIM * 2;        // 262144
  char* ws = (char*)d_ws;
  unsigned short* xg    = (unsigned short*)ws;
  unsigned short* hbuf0 = (unsigned short*)(ws + XG);
  unsigned short* hbuf1 = (unsigned short*)(ws + XG + HB);
  unsigned int*   flags = (unsigned int*)(ws + XG + 2 * HB);
  const size_t XB_OFF = XG + 2 * HB + 4096;
  const size_t WB_OFF = XB_OFF + (size_t)BDIM * TDIM * IDIM * 2;  // +64MB
  const size_t NEED   = WB_OFF + (size_t)G4 * IDIM * 2;           // +2MB

  // Zero hbuf0 (h0) + flags. hbuf1 is fully written at t=0 before first read.
  hipMemsetAsync(ws + XG, 0, HB, stream);
  hipMemsetAsync(ws + XG + 2 * HB, 0, 4096, stream);

  if (ws_size >= NEED) {
    unsigned short* xb = (unsigned short*)(ws + XB_OFF);
    unsigned short* wb = (unsigned short*)(ws + WB_OFF);
    convert_bf16<<<16896, 256, 0, stream>>>(x, W_ih, xb, wb);
    xg_gemm_bf16<<<8192, 256, 0, stream>>>(xb, wb, b_ih, b_hh, xg);
  } else {
    xg_gemm_f32<<<dim3(16, 512), 256, 0, stream>>>(x, W_ih, b_ih, b_hh, xg);
  }
  lstm_scan<<<64, 512, 0, stream>>>(W_hh, xg, hbuf0, hbuf1, flags);
  // T=256: final write (t=255, odd) went to hbuf0.
  head_kernel<<<BDIM, 64, 0, stream>>>(hbuf0, fc_w, fc_b, out);
}